// Round 8
// baseline (485.408 us; speedup 1.0000x reference)
//
#include <hip/hip_runtime.h>
#include <hip/hip_fp16.h>
#include <math.h>

// ---------------------------------------------------------------------------
// GATv2 x2 layers.
//   - CSR-by-dst via two-level counting sort (no random global atomics).
//     Self loops written at rowp[n]+cnt[n] in scan3 with mean(edge_weight).
//   - 2 dual fp32 GEMMs, 8x8 register tiling; xl stored fp16, xr fp32.
//   - Aggregation (R8): one wave per node, 4 edges per iteration.
//     lane l: group g=l>>4 -> edge e+g; q=l&15 -> channels 8q..8q+7
//     (head q>>2).  One dwordx4 fp16 gather covers 4 full rows/iter.
//     Logit: leaky folded as 0.6z+0.4|z| into 2 FMA/ch with pre-scaled att;
//     per-head sum = 2 quad_perm DPP steps; 1 exp per 4 edges.
//     Rolling prefetch: records 2 iters ahead, gather 1 iter ahead;
//     tail handled by index clamp + exp-mask.
// ---------------------------------------------------------------------------

__global__ __launch_bounds__(256) void bucket_hist_sum(
    const int* __restrict__ dst, const float* __restrict__ ew,
    int* __restrict__ bcnt, float* __restrict__ sumbuf, int E) {
    __shared__ int h[256];
    h[threadIdx.x] = 0;
    __syncthreads();
    float s = 0.f;
    for (int i = blockIdx.x * blockDim.x + threadIdx.x; i < E; i += gridDim.x * blockDim.x) {
        atomicAdd(&h[dst[i] >> 8], 1);
        s += ew[i];
    }
#pragma unroll
    for (int off = 1; off <= 32; off <<= 1)
        s += __shfl_xor(s, off, 64);
    if ((threadIdx.x & 63) == 0)
        atomicAdd(sumbuf, s);
    __syncthreads();
    int v = h[threadIdx.x];
    if (v) atomicAdd(&bcnt[threadIdx.x], v);
}

__global__ void bucket_scan(const int* __restrict__ bcnt, int* __restrict__ bbase,
                            int* __restrict__ bcur, int NBK) {
    __shared__ int sh[256];
    int t = threadIdx.x;
    int v = (t < NBK) ? bcnt[t] : 0;
    sh[t] = v;
    __syncthreads();
    for (int off = 1; off < 256; off <<= 1) {
        int y = 0;
        if (t >= off) y = sh[t - off];
        __syncthreads();
        sh[t] += y;
        __syncthreads();
    }
    int ex = sh[t] - v;
    if (t <= NBK) bbase[t] = ex;
    if (t < NBK) bcur[t] = ex;
}

__global__ __launch_bounds__(256) void partition_kernel(
    const int* __restrict__ src, const int* __restrict__ dst, const float* __restrict__ ew,
    int* __restrict__ bcur, int2* __restrict__ srec, int* __restrict__ sdst, int E) {
    __shared__ int h[256];
    __shared__ int gb[256];
    const int t = threadIdx.x;
    h[t] = 0;
    __syncthreads();
    const int base = blockIdx.x * 4096;
    int d[16], sv[16];
    float wv[16];
#pragma unroll
    for (int j = 0; j < 16; j++) {
        int i = base + t + j * 256;
        if (i < E) {
            d[j] = dst[i];
            sv[j] = src[i];
            wv[j] = ew[i];
            atomicAdd(&h[d[j] >> 8], 1);
        } else {
            d[j] = -1;
        }
    }
    __syncthreads();
    int cntt = h[t];
    if (cntt) gb[t] = atomicAdd(&bcur[t], cntt);
    h[t] = 0;
    __syncthreads();
#pragma unroll
    for (int j = 0; j < 16; j++) {
        if (d[j] >= 0) {
            int b = d[j] >> 8;
            int r = atomicAdd(&h[b], 1);
            int pos = gb[b] + r;
            srec[pos] = make_int2(sv[j], __float_as_int(wv[j]));
            sdst[pos] = d[j];
        }
    }
}

__global__ __launch_bounds__(256) void dst_hist_kernel(
    const int* __restrict__ sdst, const int* __restrict__ bbase,
    int* __restrict__ cnt, int N) {
    __shared__ int h[256];
    const int t = threadIdx.x;
    const int b = blockIdx.x;
    h[t] = 0;
    __syncthreads();
    const int e0 = bbase[b], e1 = bbase[b + 1];
    for (int i = e0 + t; i < e1; i += 256)
        atomicAdd(&h[sdst[i] & 255], 1);
    __syncthreads();
    int node = (b << 8) + t;
    if (node < N) cnt[node] = h[t];
}

__global__ void scan1_kernel(const int* __restrict__ cnt, int* __restrict__ rowp,
                             int* __restrict__ bsum, int N) {
    __shared__ int sh[256];
    int i = blockIdx.x * 256 + threadIdx.x;
    int v = (i < N) ? (cnt[i] + 1) : 0;
    sh[threadIdx.x] = v;
    __syncthreads();
    for (int off = 1; off < 256; off <<= 1) {
        int y = 0;
        if ((int)threadIdx.x >= off) y = sh[threadIdx.x - off];
        __syncthreads();
        sh[threadIdx.x] += y;
        __syncthreads();
    }
    int incl = sh[threadIdx.x];
    if (i < N) rowp[i] = incl - v;
    if (threadIdx.x == 255) bsum[blockIdx.x] = incl;
}

__global__ void scan2_kernel(int* __restrict__ bsum, int nb) {
    __shared__ int sh[256];
    int v = ((int)threadIdx.x < nb) ? bsum[threadIdx.x] : 0;
    sh[threadIdx.x] = v;
    __syncthreads();
    for (int off = 1; off < 256; off <<= 1) {
        int y = 0;
        if ((int)threadIdx.x >= off) y = sh[threadIdx.x - off];
        __syncthreads();
        sh[threadIdx.x] += y;
        __syncthreads();
    }
    int incl = sh[threadIdx.x];
    if ((int)threadIdx.x < nb) bsum[threadIdx.x] = incl - v;
}

__global__ void scan3_kernel(int* __restrict__ rowp, const int* __restrict__ bsum,
                             const int* __restrict__ cnt, const float* __restrict__ sumbuf,
                             int2* __restrict__ crec, int N, int E) {
    int i = blockIdx.x * 256 + threadIdx.x;
    if (i < N) {
        int rp = rowp[i] + bsum[blockIdx.x];
        rowp[i] = rp;
        crec[rp + cnt[i]] = make_int2(i, __float_as_int(sumbuf[0] * (1.0f / (float)E)));
    }
    if (i == 0) rowp[N] = E + N;
}

__global__ __launch_bounds__(256) void refine_kernel(
    const int2* __restrict__ srec, const int* __restrict__ sdst,
    const int* __restrict__ bbase, const int* __restrict__ rowp,
    int2* __restrict__ crec, int N) {
    __shared__ int cur[256];
    const int t = threadIdx.x;
    const int b = blockIdx.x;
    int node = (b << 8) + t;
    cur[t] = (node < N) ? rowp[node] : 0;
    __syncthreads();
    const int e0 = bbase[b], e1 = bbase[b + 1];
    for (int i = e0 + t; i < e1; i += 256) {
        int2 rec = srec[i];
        int d = sdst[i];
        int pos = atomicAdd(&cur[d & 255], 1);
        crec[pos] = rec;
    }
}

// Yh = half(X @ Wa)  [N x 128 fp16], Yb = X @ Wb  [N x 128 fp32].
__global__ __launch_bounds__(256) void gemm_dual2_kernel(
    const float* __restrict__ X, const float* __restrict__ Wa, const float* __restrict__ Wb,
    __half* __restrict__ Yh, float* __restrict__ Yb, int N) {
    __shared__ float At[32][68];   // [k][row]
    const int tid = threadIdx.x;
    const int rb = blockIdx.x * 64;
    const int tx = tid & 31;
    const int ty = tid >> 5;

    float acc[8][8];
#pragma unroll
    for (int r = 0; r < 8; r++)
#pragma unroll
        for (int c = 0; c < 8; c++) acc[r][c] = 0.f;

    for (int k0 = 0; k0 < 128; k0 += 32) {
        __syncthreads();
        for (int i = tid; i < 512; i += 256) {
            int row = i >> 3;
            int kq = i & 7;
            float4 v = make_float4(0.f, 0.f, 0.f, 0.f);
            if (rb + row < N)
                v = ((const float4*)X)[(size_t)(rb + row) * 32 + (k0 >> 2) + kq];
            At[kq * 4 + 0][row] = v.x;
            At[kq * 4 + 1][row] = v.y;
            At[kq * 4 + 2][row] = v.z;
            At[kq * 4 + 3][row] = v.w;
        }
        __syncthreads();
#pragma unroll
        for (int k = 0; k < 32; k++) {
            float4 a0 = *(const float4*)&At[k][ty * 8];
            float4 a1 = *(const float4*)&At[k][ty * 8 + 4];
            float4 b0 = ((const float4*)(Wa + (size_t)(k0 + k) * 128))[tx];
            float4 b1 = ((const float4*)(Wb + (size_t)(k0 + k) * 128))[tx];
            float ar[8] = {a0.x, a0.y, a0.z, a0.w, a1.x, a1.y, a1.z, a1.w};
            float bc[8] = {b0.x, b0.y, b0.z, b0.w, b1.x, b1.y, b1.z, b1.w};
#pragma unroll
            for (int r = 0; r < 8; r++)
#pragma unroll
                for (int c = 0; c < 8; c++)
                    acc[r][c] = fmaf(ar[r], bc[c], acc[r][c]);
        }
    }

#pragma unroll
    for (int r = 0; r < 8; r++) {
        int row = rb + ty * 8 + r;
        if (row < N) {
            __half2 h01, h23;
            h01.x = __float2half_rn(acc[r][0]); h01.y = __float2half_rn(acc[r][1]);
            h23.x = __float2half_rn(acc[r][2]); h23.y = __float2half_rn(acc[r][3]);
            __half2 hp[2] = {h01, h23};
            ((uint2*)Yh)[(size_t)row * 32 + tx] = *(uint2*)hp;   // 32 uint2/row
            ((float4*)Yb)[(size_t)row * 32 + tx] =
                make_float4(acc[r][4], acc[r][5], acc[r][6], acc[r][7]);
        }
    }
}

// DPP partial-sum step within quads/rows on the VALU pipe.
template <int CTRL>
__device__ __forceinline__ float dpp_sum_step(float v) {
    int t = __builtin_amdgcn_update_dpp(0, __float_as_int(v), CTRL, 0xF, 0xF, true);
    return v + __int_as_float(t);
}

__device__ __forceinline__ float2 cvt_h2(unsigned u) {
    __half2 h = *(__half2*)&u;
    return __half22float2(h);
}

// One wave per node; 4 edges/iteration.
// lane l: g=l>>4 (edge slot), q=l&15 -> channels 8q..8q+7 (head q>>2).
// mode 0: out[n,128] = elu(res + b)    mode 1: out[n,32] = mean_h(res) + b
__global__ __launch_bounds__(256) void agg_kernel(
    const __half* __restrict__ xlh, const float* __restrict__ xr,
    const int* __restrict__ rowp, const int2* __restrict__ crec,
    const float* __restrict__ We, const float* __restrict__ att, const float* __restrict__ bias,
    float* __restrict__ out, int N, int mode) {
    const int wid = threadIdx.x >> 6;
    const int lane = threadIdx.x & 63;
    const int n = blockIdx.x * 4 + wid;
    if (n >= N) return;
    const int g = lane >> 4;
    const int q = lane & 15;
    const int c0 = q << 3;                         // channel base, 8 per lane
    const float LOG2E = 1.4426950408889634f;

    // per-lane params for channels c0..c0+7
    float we[8], xv[8], at6[8], at4[8];
    {
        float4 wA = *(const float4*)(We + c0);
        float4 wB = *(const float4*)(We + c0 + 4);
        we[0]=wA.x; we[1]=wA.y; we[2]=wA.z; we[3]=wA.w;
        we[4]=wB.x; we[5]=wB.y; we[6]=wB.z; we[7]=wB.w;
        float4 rA = *(const float4*)(xr + (size_t)n * 128 + c0);
        float4 rB = *(const float4*)(xr + (size_t)n * 128 + c0 + 4);
        xv[0]=rA.x; xv[1]=rA.y; xv[2]=rA.z; xv[3]=rA.w;
        xv[4]=rB.x; xv[5]=rB.y; xv[6]=rB.z; xv[7]=rB.w;
        float4 aA = *(const float4*)(att + c0);
        float4 aB = *(const float4*)(att + c0 + 4);
        float av[8] = {aA.x, aA.y, aA.z, aA.w, aB.x, aB.y, aB.z, aB.w};
#pragma unroll
        for (int c = 0; c < 8; c++) {
            at6[c] = 0.6f * LOG2E * av[c];
            at4[c] = 0.4f * LOG2E * av[c];
        }
    }

    float acc[8];
#pragma unroll
    for (int c = 0; c < 8; c++) acc[c] = 0.f;
    float l0 = 0.f;

    const int e0 = __builtin_amdgcn_readfirstlane(rowp[n]);
    const int e1 = __builtin_amdgcn_readfirstlane(rowp[n + 1]);
    const int cnt = e1 - e0;
    const int T = (cnt + 3) >> 2;

    auto recload = [&](int i) -> int2 {            // edge record for this lane's group
        int idx = e0 + (i << 2) + g;
        idx = (idx < e1 - 1) ? idx : (e1 - 1);     // clamp (always valid)
        return crec[idx];
    };
    auto gatherx = [&](int s) -> int4 {            // 8 halves = 16B
        return *(const int4*)(xlh + (size_t)s * 128 + c0);
    };
    auto process = [&](int4 xh, float w, bool valid) {
        float2 x01 = cvt_h2(xh.x), x23 = cvt_h2(xh.y);
        float2 x45 = cvt_h2(xh.z), x67 = cvt_h2(xh.w);
        float xs[8] = {x01.x, x01.y, x23.x, x23.y, x45.x, x45.y, x67.x, x67.y};
        float p = 0.f;
#pragma unroll
        for (int c = 0; c < 8; c++) {
            float z = xs[c] + fmaf(w, we[c], xv[c]);
            // leaky(z)*att*log2e = at6*z + at4*|z|
            p = fmaf(at6[c], z, fmaf(at4[c], fabsf(z), p));
        }
        p = dpp_sum_step<0xB1>(p);    // quad_perm [1,0,3,2]
        p = dpp_sum_step<0x4E>(p);    // quad_perm [2,3,0,1]  -> per-head sum
        float qe = valid ? __builtin_amdgcn_exp2f(p) : 0.f;
        l0 += qe;
#pragma unroll
        for (int c = 0; c < 8; c++) acc[c] = fmaf(qe, xs[c], acc[c]);
    };

    // rolling pipeline: recs 2 ahead, gather 1 ahead
    int2 ra = recload(0);
    int2 rb = recload(1);
    int4 xa = gatherx(ra.x);
    for (int i = 0; i < T; ++i) {
        int2 rc = recload(i + 2);
        int4 xb = gatherx(rb.x);
        process(xa, __int_as_float(ra.y), (e0 + (i << 2) + g) < e1);
        ra = rb; rb = rc; xa = xb;
    }

    // combine the 4 edge groups: lanes l, l+16, l+32, l+48 hold same channels
    l0 += __shfl_xor(l0, 16, 64);
    l0 += __shfl_xor(l0, 32, 64);
#pragma unroll
    for (int c = 0; c < 8; c++) {
        acc[c] += __shfl_xor(acc[c], 16, 64);
        acc[c] += __shfl_xor(acc[c], 32, 64);
    }
    float rdenom = 1.0f / (l0 + 1e-16f);
    float r[8];
#pragma unroll
    for (int c = 0; c < 8; c++) r[c] = acc[c] * rdenom;

    if (mode == 0) {
        if (g == 0) {
            float4 bA = *(const float4*)(bias + c0);
            float4 bB = *(const float4*)(bias + c0 + 4);
            float bv[8] = {bA.x, bA.y, bA.z, bA.w, bB.x, bB.y, bB.z, bB.w};
            float o[8];
#pragma unroll
            for (int c = 0; c < 8; c++) {
                float v = r[c] + bv[c];
                o[c] = (v > 0.f) ? v : (__expf(v) - 1.f);   // ELU
            }
            float* op = out + (size_t)n * 128 + c0;
            *(float4*)op       = make_float4(o[0], o[1], o[2], o[3]);
            *(float4*)(op + 4) = make_float4(o[4], o[5], o[6], o[7]);
        }
    } else {
        // mean over heads: lanes q, q^4, q^8 (+12) hold same within-head cols
#pragma unroll
        for (int c = 0; c < 8; c++) {
            r[c] += __shfl_xor(r[c], 4, 64);
            r[c] += __shfl_xor(r[c], 8, 64);
        }
        if (lane < 4) {
            int w0 = lane << 3;                    // within-head col base
            float4 bA = *(const float4*)(bias + w0);
            float4 bB = *(const float4*)(bias + w0 + 4);
            float bv[8] = {bA.x, bA.y, bA.z, bA.w, bB.x, bB.y, bB.z, bB.w};
            float o[8];
#pragma unroll
            for (int c = 0; c < 8; c++) o[c] = 0.25f * r[c] + bv[c];
            float* op = out + (size_t)n * 32 + w0;
            *(float4*)op       = make_float4(o[0], o[1], o[2], o[3]);
            *(float4*)(op + 4) = make_float4(o[4], o[5], o[6], o[7]);
        }
    }
}

extern "C" void kernel_launch(void* const* d_in, const int* in_sizes, int n_in,
                              void* d_out, int out_size, void* d_ws, size_t ws_size,
                              hipStream_t stream) {
    const float* x    = (const float*)d_in[0];
    const int*  eidx  = (const int*)d_in[1];
    const float* ew   = (const float*)d_in[2];
    const float* Wl1  = (const float*)d_in[3];
    const float* Wr1  = (const float*)d_in[4];
    const float* We1  = (const float*)d_in[5];
    const float* att1 = (const float*)d_in[6];
    const float* b1   = (const float*)d_in[7];
    const float* Wl2  = (const float*)d_in[8];
    const float* Wr2  = (const float*)d_in[9];
    const float* We2  = (const float*)d_in[10];
    const float* att2 = (const float*)d_in[11];
    const float* b2   = (const float*)d_in[12];

    const int N = in_sizes[0] / 128;
    const int E = in_sizes[1] / 2;
    const int* src = eidx;
    const int* dst = eidx + E;
    const int NBK = (N + 255) >> 8;

    char* p = (char*)d_ws;
    auto alloc = [&](size_t bytes) -> void* {
        void* r = (void*)p;
        p += (bytes + 255) & ~(size_t)255;
        return r;
    };
    __half* xlh   = (__half*)alloc((size_t)N * 128 * sizeof(__half));
    float* xr     = (float*)alloc((size_t)N * 128 * sizeof(float));
    float* h1     = (float*)alloc((size_t)N * 128 * sizeof(float));
    int2*  crec   = (int2*)alloc((size_t)(E + N) * sizeof(int2));
    int*   rowp   = (int*)alloc((size_t)(N + 1) * sizeof(int));
    int*   cnt    = (int*)alloc((size_t)N * sizeof(int));
    int*   bcnt   = (int*)alloc(260 * sizeof(int));
    float* sumbuf = (float*)(bcnt + 256);
    int*   bbase  = (int*)alloc(260 * sizeof(int));
    int*   bcur   = (int*)alloc(260 * sizeof(int));
    int*   bsum   = (int*)alloc(256 * sizeof(int));
    int2*  srec   = (int2*)h1;                      // staging aliased into h1
    int*   sdst   = (int*)((char*)h1 + (size_t)E * sizeof(int2));

    hipMemsetAsync(bcnt, 0, 260 * sizeof(int), stream);

    bucket_hist_sum<<<1024, 256, 0, stream>>>(dst, ew, bcnt, sumbuf, E);
    bucket_scan<<<1, 256, 0, stream>>>(bcnt, bbase, bcur, NBK);
    partition_kernel<<<(E + 4095) / 4096, 256, 0, stream>>>(src, dst, ew, bcur,
                                                            srec, sdst, E);
    dst_hist_kernel<<<NBK, 256, 0, stream>>>(sdst, bbase, cnt, N);

    int nb = (N + 255) / 256;
    scan1_kernel<<<nb, 256, 0, stream>>>(cnt, rowp, bsum, N);
    scan2_kernel<<<1, 256, 0, stream>>>(bsum, nb);
    scan3_kernel<<<nb, 256, 0, stream>>>(rowp, bsum, cnt, sumbuf, crec, N, E);

    refine_kernel<<<NBK, 256, 0, stream>>>(srec, sdst, bbase, rowp, crec, N);

    // Layer 1
    gemm_dual2_kernel<<<(N + 63) / 64, 256, 0, stream>>>(x, Wl1, Wr1, xlh, xr, N);
    agg_kernel<<<(N + 3) / 4, 256, 0, stream>>>(xlh, xr, rowp, crec,
                                                We1, att1, b1, h1, N, 0);
    // Layer 2
    gemm_dual2_kernel<<<(N + 63) / 64, 256, 0, stream>>>(h1, Wl2, Wr2, xlh, xr, N);
    agg_kernel<<<(N + 3) / 4, 256, 0, stream>>>(xlh, xr, rowp, crec,
                                                We2, att2, b2, (float*)d_out, N, 1);
}

// Round 9
// 444.455 us; speedup vs baseline: 1.0921x; 1.0921x over previous
//
#include <hip/hip_runtime.h>
#include <hip/hip_fp16.h>
#include <math.h>

// ---------------------------------------------------------------------------
// GATv2 x2 layers.
//   - CSR-by-dst via two-level counting sort (no random global atomics).
//     srec.x packs src (bits 0..19) | dst&255 (bits 20..27) -> no sdst array.
//     Self loops written at rowp[n]+cnt[n] in scan3 with mean(edge_weight).
//   - 2 dual fp32 GEMMs, 8x8 register tiling; xl stored fp16, xr fp32.
//   - Aggregation: one wave per node, 4 edges/iter (R8 layout), with a
//     DEEP rolling pipeline (R9): records 4 iters ahead, gathers 2 ahead,
//     so the rec->gather->use chain is covered at ~200-400cyc VMEM latency.
// ---------------------------------------------------------------------------

__global__ __launch_bounds__(256) void bucket_hist_sum(
    const int* __restrict__ dst, const float* __restrict__ ew,
    int* __restrict__ bcnt, float* __restrict__ sumbuf, int E) {
    __shared__ int h[256];
    h[threadIdx.x] = 0;
    __syncthreads();
    float s = 0.f;
    for (int i = blockIdx.x * blockDim.x + threadIdx.x; i < E; i += gridDim.x * blockDim.x) {
        atomicAdd(&h[dst[i] >> 8], 1);
        s += ew[i];
    }
#pragma unroll
    for (int off = 1; off <= 32; off <<= 1)
        s += __shfl_xor(s, off, 64);
    if ((threadIdx.x & 63) == 0)
        atomicAdd(sumbuf, s);
    __syncthreads();
    int v = h[threadIdx.x];
    if (v) atomicAdd(&bcnt[threadIdx.x], v);
}

__global__ void bucket_scan(const int* __restrict__ bcnt, int* __restrict__ bbase,
                            int* __restrict__ bcur, int NBK) {
    __shared__ int sh[256];
    int t = threadIdx.x;
    int v = (t < NBK) ? bcnt[t] : 0;
    sh[t] = v;
    __syncthreads();
    for (int off = 1; off < 256; off <<= 1) {
        int y = 0;
        if (t >= off) y = sh[t - off];
        __syncthreads();
        sh[t] += y;
        __syncthreads();
    }
    int ex = sh[t] - v;
    if (t <= NBK) bbase[t] = ex;
    if (t < NBK) bcur[t] = ex;
}

__global__ __launch_bounds__(256) void partition_kernel(
    const int* __restrict__ src, const int* __restrict__ dst, const float* __restrict__ ew,
    int* __restrict__ bcur, int2* __restrict__ srec, int E) {
    __shared__ int h[256];
    __shared__ int gb[256];
    const int t = threadIdx.x;
    h[t] = 0;
    __syncthreads();
    const int base = blockIdx.x * 4096;
    int d[16], sv[16];
    float wv[16];
#pragma unroll
    for (int j = 0; j < 16; j++) {
        int i = base + t + j * 256;
        if (i < E) {
            d[j] = dst[i];
            sv[j] = src[i];
            wv[j] = ew[i];
            atomicAdd(&h[d[j] >> 8], 1);
        } else {
            d[j] = -1;
        }
    }
    __syncthreads();
    int cntt = h[t];
    if (cntt) gb[t] = atomicAdd(&bcur[t], cntt);
    h[t] = 0;
    __syncthreads();
#pragma unroll
    for (int j = 0; j < 16; j++) {
        if (d[j] >= 0) {
            int b = d[j] >> 8;
            int r = atomicAdd(&h[b], 1);
            int pos = gb[b] + r;
            // pack src (bits 0..19) | (dst&255) << 20
            srec[pos] = make_int2(sv[j] | ((d[j] & 255) << 20), __float_as_int(wv[j]));
        }
    }
}

__global__ __launch_bounds__(256) void dst_hist_kernel(
    const int2* __restrict__ srec, const int* __restrict__ bbase,
    int* __restrict__ cnt, int N) {
    __shared__ int h[256];
    const int t = threadIdx.x;
    const int b = blockIdx.x;
    h[t] = 0;
    __syncthreads();
    const int e0 = bbase[b], e1 = bbase[b + 1];
    for (int i = e0 + t; i < e1; i += 256)
        atomicAdd(&h[(srec[i].x >> 20) & 255], 1);
    __syncthreads();
    int node = (b << 8) + t;
    if (node < N) cnt[node] = h[t];
}

__global__ void scan1_kernel(const int* __restrict__ cnt, int* __restrict__ rowp,
                             int* __restrict__ bsum, int N) {
    __shared__ int sh[256];
    int i = blockIdx.x * 256 + threadIdx.x;
    int v = (i < N) ? (cnt[i] + 1) : 0;
    sh[threadIdx.x] = v;
    __syncthreads();
    for (int off = 1; off < 256; off <<= 1) {
        int y = 0;
        if ((int)threadIdx.x >= off) y = sh[threadIdx.x - off];
        __syncthreads();
        sh[threadIdx.x] += y;
        __syncthreads();
    }
    int incl = sh[threadIdx.x];
    if (i < N) rowp[i] = incl - v;
    if (threadIdx.x == 255) bsum[blockIdx.x] = incl;
}

__global__ void scan2_kernel(int* __restrict__ bsum, int nb) {
    __shared__ int sh[256];
    int v = ((int)threadIdx.x < nb) ? bsum[threadIdx.x] : 0;
    sh[threadIdx.x] = v;
    __syncthreads();
    for (int off = 1; off < 256; off <<= 1) {
        int y = 0;
        if ((int)threadIdx.x >= off) y = sh[threadIdx.x - off];
        __syncthreads();
        sh[threadIdx.x] += y;
        __syncthreads();
    }
    int incl = sh[threadIdx.x];
    if ((int)threadIdx.x < nb) bsum[threadIdx.x] = incl - v;
}

__global__ void scan3_kernel(int* __restrict__ rowp, const int* __restrict__ bsum,
                             const int* __restrict__ cnt, const float* __restrict__ sumbuf,
                             int2* __restrict__ crec, int N, int E) {
    int i = blockIdx.x * 256 + threadIdx.x;
    if (i < N) {
        int rp = rowp[i] + bsum[blockIdx.x];
        rowp[i] = rp;
        crec[rp + cnt[i]] = make_int2(i, __float_as_int(sumbuf[0] * (1.0f / (float)E)));
    }
    if (i == 0) rowp[N] = E + N;
}

__global__ __launch_bounds__(256) void refine_kernel(
    const int2* __restrict__ srec, const int* __restrict__ bbase,
    const int* __restrict__ rowp, int2* __restrict__ crec, int N) {
    __shared__ int cur[256];
    const int t = threadIdx.x;
    const int b = blockIdx.x;
    int node = (b << 8) + t;
    cur[t] = (node < N) ? rowp[node] : 0;
    __syncthreads();
    const int e0 = bbase[b], e1 = bbase[b + 1];
    for (int i = e0 + t; i < e1; i += 256) {
        int2 rec = srec[i];
        int dlow = (rec.x >> 20) & 255;
        int pos = atomicAdd(&cur[dlow], 1);
        crec[pos] = make_int2(rec.x & 0xFFFFF, rec.y);
    }
}

// Yh = half(X @ Wa)  [N x 128 fp16], Yb = X @ Wb  [N x 128 fp32].
__global__ __launch_bounds__(256) void gemm_dual2_kernel(
    const float* __restrict__ X, const float* __restrict__ Wa, const float* __restrict__ Wb,
    __half* __restrict__ Yh, float* __restrict__ Yb, int N) {
    __shared__ float At[32][68];   // [k][row]
    const int tid = threadIdx.x;
    const int rb = blockIdx.x * 64;
    const int tx = tid & 31;
    const int ty = tid >> 5;

    float acc[8][8];
#pragma unroll
    for (int r = 0; r < 8; r++)
#pragma unroll
        for (int c = 0; c < 8; c++) acc[r][c] = 0.f;

    for (int k0 = 0; k0 < 128; k0 += 32) {
        __syncthreads();
        for (int i = tid; i < 512; i += 256) {
            int row = i >> 3;
            int kq = i & 7;
            float4 v = make_float4(0.f, 0.f, 0.f, 0.f);
            if (rb + row < N)
                v = ((const float4*)X)[(size_t)(rb + row) * 32 + (k0 >> 2) + kq];
            At[kq * 4 + 0][row] = v.x;
            At[kq * 4 + 1][row] = v.y;
            At[kq * 4 + 2][row] = v.z;
            At[kq * 4 + 3][row] = v.w;
        }
        __syncthreads();
#pragma unroll
        for (int k = 0; k < 32; k++) {
            float4 a0 = *(const float4*)&At[k][ty * 8];
            float4 a1 = *(const float4*)&At[k][ty * 8 + 4];
            float4 b0 = ((const float4*)(Wa + (size_t)(k0 + k) * 128))[tx];
            float4 b1 = ((const float4*)(Wb + (size_t)(k0 + k) * 128))[tx];
            float ar[8] = {a0.x, a0.y, a0.z, a0.w, a1.x, a1.y, a1.z, a1.w};
            float bc[8] = {b0.x, b0.y, b0.z, b0.w, b1.x, b1.y, b1.z, b1.w};
#pragma unroll
            for (int r = 0; r < 8; r++)
#pragma unroll
                for (int c = 0; c < 8; c++)
                    acc[r][c] = fmaf(ar[r], bc[c], acc[r][c]);
        }
    }

#pragma unroll
    for (int r = 0; r < 8; r++) {
        int row = rb + ty * 8 + r;
        if (row < N) {
            __half2 h01, h23;
            h01.x = __float2half_rn(acc[r][0]); h01.y = __float2half_rn(acc[r][1]);
            h23.x = __float2half_rn(acc[r][2]); h23.y = __float2half_rn(acc[r][3]);
            __half2 hp[2] = {h01, h23};
            ((uint2*)Yh)[(size_t)row * 32 + tx] = *(uint2*)hp;   // 32 uint2/row
            ((float4*)Yb)[(size_t)row * 32 + tx] =
                make_float4(acc[r][4], acc[r][5], acc[r][6], acc[r][7]);
        }
    }
}

// DPP partial-sum step within quads on the VALU pipe.
template <int CTRL>
__device__ __forceinline__ float dpp_sum_step(float v) {
    int t = __builtin_amdgcn_update_dpp(0, __float_as_int(v), CTRL, 0xF, 0xF, true);
    return v + __int_as_float(t);
}

__device__ __forceinline__ float2 cvt_h2(unsigned u) {
    __half2 h = *(__half2*)&u;
    return __half22float2(h);
}

// One wave per node; 4 edges/iteration.
// lane l: g=l>>4 (edge slot), q=l&15 -> channels 8q..8q+7 (head q>>2).
// Pipeline: records 4 iters ahead, gathers 2 iters ahead.
__global__ __launch_bounds__(256) void agg_kernel(
    const __half* __restrict__ xlh, const float* __restrict__ xr,
    const int* __restrict__ rowp, const int2* __restrict__ crec,
    const float* __restrict__ We, const float* __restrict__ att, const float* __restrict__ bias,
    float* __restrict__ out, int N, int mode) {
    const int wid = threadIdx.x >> 6;
    const int lane = threadIdx.x & 63;
    const int n = blockIdx.x * 4 + wid;
    if (n >= N) return;
    const int g = lane >> 4;
    const int q = lane & 15;
    const int c0 = q << 3;                         // channel base, 8 per lane
    const float LOG2E = 1.4426950408889634f;

    float we[8], xv[8], at6[8], at4[8];
    {
        float4 wA = *(const float4*)(We + c0);
        float4 wB = *(const float4*)(We + c0 + 4);
        we[0]=wA.x; we[1]=wA.y; we[2]=wA.z; we[3]=wA.w;
        we[4]=wB.x; we[5]=wB.y; we[6]=wB.z; we[7]=wB.w;
        float4 rA = *(const float4*)(xr + (size_t)n * 128 + c0);
        float4 rB = *(const float4*)(xr + (size_t)n * 128 + c0 + 4);
        xv[0]=rA.x; xv[1]=rA.y; xv[2]=rA.z; xv[3]=rA.w;
        xv[4]=rB.x; xv[5]=rB.y; xv[6]=rB.z; xv[7]=rB.w;
        float4 aA = *(const float4*)(att + c0);
        float4 aB = *(const float4*)(att + c0 + 4);
        float av[8] = {aA.x, aA.y, aA.z, aA.w, aB.x, aB.y, aB.z, aB.w};
#pragma unroll
        for (int c = 0; c < 8; c++) {
            at6[c] = 0.6f * LOG2E * av[c];
            at4[c] = 0.4f * LOG2E * av[c];
        }
    }

    float acc[8];
#pragma unroll
    for (int c = 0; c < 8; c++) acc[c] = 0.f;
    float l0 = 0.f;

    const int e0 = __builtin_amdgcn_readfirstlane(rowp[n]);
    const int e1 = __builtin_amdgcn_readfirstlane(rowp[n + 1]);
    const int cnt = e1 - e0;
    const int T = (cnt + 3) >> 2;

    auto recload = [&](int i) -> int2 {
        int idx = e0 + (i << 2) + g;
        idx = (idx < e1 - 1) ? idx : (e1 - 1);     // clamp (always valid)
        return crec[idx];
    };
    auto gatherx = [&](int s) -> int4 {            // 8 halves = 16B
        return *(const int4*)(xlh + (size_t)s * 128 + c0);
    };
    auto process = [&](int4 xh, float w, bool valid) {
        float2 x01 = cvt_h2(xh.x), x23 = cvt_h2(xh.y);
        float2 x45 = cvt_h2(xh.z), x67 = cvt_h2(xh.w);
        float xs[8] = {x01.x, x01.y, x23.x, x23.y, x45.x, x45.y, x67.x, x67.y};
        float p = 0.f;
#pragma unroll
        for (int c = 0; c < 8; c++) {
            float z = xs[c] + fmaf(w, we[c], xv[c]);
            p = fmaf(at6[c], z, fmaf(at4[c], fabsf(z), p));  // leaky folded
        }
        p = dpp_sum_step<0xB1>(p);    // quad_perm [1,0,3,2]
        p = dpp_sum_step<0x4E>(p);    // quad_perm [2,3,0,1]  -> per-head sum
        float qe = valid ? __builtin_amdgcn_exp2f(p) : 0.f;
        l0 += qe;
#pragma unroll
        for (int c = 0; c < 8; c++) acc[c] = fmaf(qe, xs[c], acc[c]);
    };

    // deep rolling pipeline: records 4 ahead, gathers 2 ahead
    int2 r0 = recload(0), r1 = recload(1), r2 = recload(2), r3 = recload(3);
    int4 x0 = gatherx(r0.x), x1 = gatherx(r1.x);
    for (int i = 0; i < T; ++i) {
        int2 r4 = recload(i + 4);
        int4 x2 = gatherx(r2.x);
        process(x0, __int_as_float(r0.y), (e0 + (i << 2) + g) < e1);
        r0 = r1; r1 = r2; r2 = r3; r3 = r4;
        x0 = x1; x1 = x2;
    }

    // combine the 4 edge groups
    l0 += __shfl_xor(l0, 16, 64);
    l0 += __shfl_xor(l0, 32, 64);
#pragma unroll
    for (int c = 0; c < 8; c++) {
        acc[c] += __shfl_xor(acc[c], 16, 64);
        acc[c] += __shfl_xor(acc[c], 32, 64);
    }
    float rdenom = 1.0f / (l0 + 1e-16f);
    float r[8];
#pragma unroll
    for (int c = 0; c < 8; c++) r[c] = acc[c] * rdenom;

    if (mode == 0) {
        if (g == 0) {
            float4 bA = *(const float4*)(bias + c0);
            float4 bB = *(const float4*)(bias + c0 + 4);
            float bv[8] = {bA.x, bA.y, bA.z, bA.w, bB.x, bB.y, bB.z, bB.w};
            float o[8];
#pragma unroll
            for (int c = 0; c < 8; c++) {
                float v = r[c] + bv[c];
                o[c] = (v > 0.f) ? v : (__expf(v) - 1.f);   // ELU
            }
            float* op = out + (size_t)n * 128 + c0;
            *(float4*)op       = make_float4(o[0], o[1], o[2], o[3]);
            *(float4*)(op + 4) = make_float4(o[4], o[5], o[6], o[7]);
        }
    } else {
#pragma unroll
        for (int c = 0; c < 8; c++) {
            r[c] += __shfl_xor(r[c], 4, 64);
            r[c] += __shfl_xor(r[c], 8, 64);
        }
        if (lane < 4) {
            int w0 = lane << 3;
            float4 bA = *(const float4*)(bias + w0);
            float4 bB = *(const float4*)(bias + w0 + 4);
            float bv[8] = {bA.x, bA.y, bA.z, bA.w, bB.x, bB.y, bB.z, bB.w};
            float o[8];
#pragma unroll
            for (int c = 0; c < 8; c++) o[c] = 0.25f * r[c] + bv[c];
            float* op = out + (size_t)n * 32 + w0;
            *(float4*)op       = make_float4(o[0], o[1], o[2], o[3]);
            *(float4*)(op + 4) = make_float4(o[4], o[5], o[6], o[7]);
        }
    }
}

extern "C" void kernel_launch(void* const* d_in, const int* in_sizes, int n_in,
                              void* d_out, int out_size, void* d_ws, size_t ws_size,
                              hipStream_t stream) {
    const float* x    = (const float*)d_in[0];
    const int*  eidx  = (const int*)d_in[1];
    const float* ew   = (const float*)d_in[2];
    const float* Wl1  = (const float*)d_in[3];
    const float* Wr1  = (const float*)d_in[4];
    const float* We1  = (const float*)d_in[5];
    const float* att1 = (const float*)d_in[6];
    const float* b1   = (const float*)d_in[7];
    const float* Wl2  = (const float*)d_in[8];
    const float* Wr2  = (const float*)d_in[9];
    const float* We2  = (const float*)d_in[10];
    const float* att2 = (const float*)d_in[11];
    const float* b2   = (const float*)d_in[12];

    const int N = in_sizes[0] / 128;
    const int E = in_sizes[1] / 2;
    const int* src = eidx;
    const int* dst = eidx + E;
    const int NBK = (N + 255) >> 8;

    char* p = (char*)d_ws;
    auto alloc = [&](size_t bytes) -> void* {
        void* r = (void*)p;
        p += (bytes + 255) & ~(size_t)255;
        return r;
    };
    __half* xlh   = (__half*)alloc((size_t)N * 128 * sizeof(__half));
    float* xr     = (float*)alloc((size_t)N * 128 * sizeof(float));
    float* h1     = (float*)alloc((size_t)N * 128 * sizeof(float));
    int2*  crec   = (int2*)alloc((size_t)(E + N) * sizeof(int2));
    int*   rowp   = (int*)alloc((size_t)(N + 1) * sizeof(int));
    int*   cnt    = (int*)alloc((size_t)N * sizeof(int));
    int*   bcnt   = (int*)alloc(260 * sizeof(int));
    float* sumbuf = (float*)(bcnt + 256);
    int*   bbase  = (int*)alloc(260 * sizeof(int));
    int*   bcur   = (int*)alloc(260 * sizeof(int));
    int*   bsum   = (int*)alloc(256 * sizeof(int));
    int2*  srec   = (int2*)h1;                      // staging aliased into h1

    hipMemsetAsync(bcnt, 0, 260 * sizeof(int), stream);

    bucket_hist_sum<<<1024, 256, 0, stream>>>(dst, ew, bcnt, sumbuf, E);
    bucket_scan<<<1, 256, 0, stream>>>(bcnt, bbase, bcur, NBK);
    partition_kernel<<<(E + 4095) / 4096, 256, 0, stream>>>(src, dst, ew, bcur, srec, E);
    dst_hist_kernel<<<NBK, 256, 0, stream>>>(srec, bbase, cnt, N);

    int nb = (N + 255) / 256;
    scan1_kernel<<<nb, 256, 0, stream>>>(cnt, rowp, bsum, N);
    scan2_kernel<<<1, 256, 0, stream>>>(bsum, nb);
    scan3_kernel<<<nb, 256, 0, stream>>>(rowp, bsum, cnt, sumbuf, crec, N, E);

    refine_kernel<<<NBK, 256, 0, stream>>>(srec, bbase, rowp, crec, N);

    // Layer 1
    gemm_dual2_kernel<<<(N + 63) / 64, 256, 0, stream>>>(x, Wl1, Wr1, xlh, xr, N);
    agg_kernel<<<(N + 3) / 4, 256, 0, stream>>>(xlh, xr, rowp, crec,
                                                We1, att1, b1, h1, N, 0);
    // Layer 2
    gemm_dual2_kernel<<<(N + 63) / 64, 256, 0, stream>>>(h1, Wl2, Wr2, xlh, xr, N);
    agg_kernel<<<(N + 3) / 4, 256, 0, stream>>>(xlh, xr, rowp, crec,
                                                We2, att2, b2, (float*)d_out, N, 1);
}